// Round 1
// baseline (403.630 us; speedup 1.0000x reference)
//
#include <hip/hip_runtime.h>
#include <hip/hip_bf16.h>

// Problem constants (from reference)
#define BATCH 8
#define NH    8
#define HD    32
#define WIN   512    // 64 x 8 tokens per vertical-stripe window
#define DIM   256
#define RESO  64
#define SEQL  4096
#define VSTRIDE 520  // Vt padded token stride (bf16 elements)
#define WPAD  264    // proj W LDS row stride (bf16 elements)

#define LOG2E 1.44269504088896340736f

extern "C" __device__ float __ocml_native_exp2_f32(float);   // raw v_exp_f32

typedef __attribute__((ext_vector_type(8))) short short8;   // 8 bf16 (4 VGPRs) MFMA A/B frag
typedef __attribute__((ext_vector_type(4))) float floatx4;  // MFMA C/D frag

__device__ __forceinline__ unsigned short f2bf(float f) {
    union { float f; unsigned int i; } x; x.f = f;
    unsigned int r = x.i + 0x7fff + ((x.i >> 16) & 1);   // round-to-nearest-even
    return (unsigned short)(r >> 16);
}
__device__ __forceinline__ float bf2f(unsigned short u) {
    union { unsigned int i; float f; } x; x.i = ((unsigned int)u) << 16; return x.f;
}
__device__ __forceinline__ unsigned int pk2(float lo, float hi) {      // RNE pack
    return ((unsigned int)f2bf(hi) << 16) | (unsigned int)f2bf(lo);
}
__device__ __forceinline__ unsigned int pk2t(float lo, float hi) {     // truncation pack, 1 v_perm
    union { float f; unsigned int i; } a, b; a.f = lo; b.f = hi;
    return __builtin_amdgcn_perm(b.i, a.i, 0x07060302);                // {hi[3],hi[2],lo[3],lo[2]}
}
__device__ __forceinline__ void unp2(unsigned int u, float& lo, float& hi) {
    union { unsigned int i; float f; } a, b;
    a.i = u << 16; b.i = u & 0xffff0000u;
    lo = a.f; hi = b.f;
}

union FragU {
    unsigned int  u[4];
    unsigned short us[8];
    short8        s;
    ushort4       v4[2];
};

// ---------------------------------------------------------------------------
// MFMA flash attention + LePE. Grid: 512 blocks (64 win x 8 heads) x 1024 thr
// (16 waves). Wave w owns query rows w*32..w*32+31 (2 q-tiles of 16).
// LDS (66 KiB) caps residency at 2 blocks/CU; 1024-thread blocks make that
// 32 waves/CU (100% occupancy) instead of 16 — the kernel is latency-bound
// (MfmaUtil 8.5%, VALUBusy 38%, HBM 11% at 512 thr), so we double the
// latency-hiding wave pool at constant total work.
// Q pre-scaled by scale*log2e -> scores arrive in log2 domain; p = v_exp_f32.
// S^T tiles via mfma_16x16x32 (A=K from swizzled LDS, B=Q^T from global);
// exp'd P feeds PV mfma directly from registers (S^T C-layout == B-layout
// under the key permutation absorbed into the V^T fragment reads).
// ---------------------------------------------------------------------------
__global__ __launch_bounds__(1024, 8)
void attn_mfma_kernel(const float* __restrict__ qkv,
                      const float* __restrict__ scale_p,
                      const float* __restrict__ conv_w,
                      const float* __restrict__ conv_b,
                      unsigned short* __restrict__ X)
{
    __shared__ alignas(16) unsigned short Klds[WIN * HD];      // swizzled 16B chunks
    __shared__ alignas(16) unsigned short Vt[HD * VSTRIDE];    // V^T, padded
    __shared__ float cw[HD * 9];
    __shared__ float cb[HD];

    const int wh   = blockIdx.x;
    const int bw   = wh >> 3;        // global window 0..63
    const int head = wh & 7;
    const int b    = bw >> 3;
    const int wx   = bw & 7;
    const int tid  = threadIdx.x;

    const float scale = scale_p[0] * LOG2E;    // log2-domain logits
    const size_t plane = (size_t)BATCH * SEQL * DIM;
    const float* qg = qkv;
    const float* kg = qkv + plane;
    const float* vg = qkv + 2 * plane;

    // ---- Stage K (bf16 trunc, XOR-swizzled 16B chunks) ----
    for (int idx = tid; idx < WIN * 4; idx += 1024) {
        const int t = idx >> 2, c8 = idx & 3;
        const size_t goff = ((size_t)b * SEQL + (size_t)(t >> 3) * RESO + wx * 8 + (t & 7)) * DIM
                          + head * HD + c8 * 8;
        const float4 k0 = *(const float4*)(kg + goff);
        const float4 k1 = *(const float4*)(kg + goff + 4);
        uint4 pk;
        pk.x = pk2t(k0.x, k0.y); pk.y = pk2t(k0.z, k0.w);
        pk.z = pk2t(k1.x, k1.y); pk.w = pk2t(k1.z, k1.w);
        const int p = c8 ^ ((t >> 1) & 3);
        *(uint4*)&Klds[t * HD + p * 8] = pk;
    }
    // ---- Stage V^T (bf16 RNE, padded stride; token pairs packed as b32) ----
    for (int idx = tid; idx < 256 * HD; idx += 1024) {
        const int ch = idx & 31, tp = idx >> 5;
        const int t = tp * 2;
        const size_t goff = ((size_t)b * SEQL + (size_t)(t >> 3) * RESO + wx * 8 + (t & 7)) * DIM
                          + head * HD + ch;
        const float v0 = vg[goff];
        const float v1 = vg[goff + DIM];       // token t+1 (same image row)
        *(unsigned int*)&Vt[ch * VSTRIDE + t] = pk2(v0, v1);
    }
    if (tid < HD * 9) cw[tid] = conv_w[head * HD * 9 + tid];
    if (tid < HD) cb[tid] = conv_b[head * HD + tid];

    const int lane = tid & 63, wid = tid >> 6;     // wid 0..15
    const int q4 = lane >> 4, nn = lane & 15;
    const int qbase = wid * 32;
    const bool mwin = (wx == 7);

    // ---- Q B-frags (2 q-tiles), pre-scaled (log2e folded), bf16 trunc ----
    // Issued BEFORE the barrier so the global-load latency overlaps the wait.
    short8 qf[2];
    #pragma unroll
    for (int qq = 0; qq < 2; ++qq) {
        const int t = qbase + qq * 16 + nn;
        const size_t goff = ((size_t)b * SEQL + (size_t)(t >> 3) * RESO + wx * 8 + (t & 7)) * DIM
                          + head * HD + q4 * 8;
        const float4 a = *(const float4*)(qg + goff);
        const float4 c = *(const float4*)(qg + goff + 4);
        FragU f;
        f.u[0] = pk2t(a.x * scale, a.y * scale);
        f.u[1] = pk2t(a.z * scale, a.w * scale);
        f.u[2] = pk2t(c.x * scale, c.y * scale);
        f.u[3] = pk2t(c.z * scale, c.w * scale);
        qf[qq] = f.s;
    }
    __syncthreads();

    // mask add (only stripe wx==7): key group vs query group, lane-constant
    float mk[4];
    #pragma unroll
    for (int r = 0; r < 4; ++r) {
        const bool kgrp = (((q4 * 4 + r) & 7) < 4);
        const bool qgrp = ((nn & 7) < 4);
        mk[r] = (kgrp != qgrp) ? (-100.f * LOG2E) : 0.f;
    }

    floatx4 acc[2][2];
    #pragma unroll
    for (int qq = 0; qq < 2; ++qq) {
        acc[qq][0] = (floatx4){0.f, 0.f, 0.f, 0.f};
        acc[qq][1] = (floatx4){0.f, 0.f, 0.f, 0.f};
    }
    float rs[2] = {0.f, 0.f};
    const floatx4 zf = (floatx4){0.f, 0.f, 0.f, 0.f};

    // ---- main K loop: 16 chunks of 32 keys (2 j-tiles each) ----
    for (int kc = 0; kc < 16; ++kc) {
        short8 kf0, kf1;
        {
            const int t0 = (2 * kc) * 16 + nn;
            const int t1 = (2 * kc + 1) * 16 + nn;
            kf0 = *(const short8*)&Klds[t0 * HD + (q4 ^ ((t0 >> 1) & 3)) * 8];
            kf1 = *(const short8*)&Klds[t1 * HD + (q4 ^ ((t1 >> 1) & 3)) * 8];
        }
        short8 vf[2];
        #pragma unroll
        for (int nt = 0; nt < 2; ++nt) {
            const int ch = nt * 16 + nn;
            FragU f;
            f.v4[0] = *(const ushort4*)&Vt[ch * VSTRIDE + kc * 32 + q4 * 4];
            f.v4[1] = *(const ushort4*)&Vt[ch * VSTRIDE + kc * 32 + 16 + q4 * 4];
            vf[nt] = f.s;
        }
        #pragma unroll
        for (int qq = 0; qq < 2; ++qq) {
            floatx4 s0 = __builtin_amdgcn_mfma_f32_16x16x32_bf16(kf0, qf[qq], zf, 0, 0, 0);
            floatx4 s1 = __builtin_amdgcn_mfma_f32_16x16x32_bf16(kf1, qf[qq], zf, 0, 0, 0);
            if (mwin) {                              // wave-uniform branch (1/8 blocks)
                #pragma unroll
                for (int r = 0; r < 4; ++r) { s0[r] += mk[r]; s1[r] += mk[r]; }
            }
            float p[8];
            #pragma unroll
            for (int r = 0; r < 4; ++r) {
                p[r]     = __ocml_native_exp2_f32(s0[r]);   // single v_exp_f32
                p[4 + r] = __ocml_native_exp2_f32(s1[r]);
            }
            rs[qq] += ((p[0] + p[1]) + (p[2] + p[3])) + ((p[4] + p[5]) + (p[6] + p[7]));
            FragU pf;                                // truncation pack: 1 v_perm each
            pf.u[0] = pk2t(p[0], p[1]);
            pf.u[1] = pk2t(p[2], p[3]);
            pf.u[2] = pk2t(p[4], p[5]);
            pf.u[3] = pk2t(p[6], p[7]);
            acc[qq][0] = __builtin_amdgcn_mfma_f32_16x16x32_bf16(vf[0], pf.s, acc[qq][0], 0, 0, 0);
            acc[qq][1] = __builtin_amdgcn_mfma_f32_16x16x32_bf16(vf[1], pf.s, acc[qq][1], 0, 0, 0);
        }
    }

    // ---- row sums across quads; lane-aligned with PV C-layout columns ----
    float inv[2];
    #pragma unroll
    for (int qq = 0; qq < 2; ++qq) {
        float v = rs[qq];
        v += __shfl_xor(v, 16);
        v += __shfl_xor(v, 32);
        inv[qq] = 1.0f / v;
    }

    // ---- epilogue: normalize, +conv bias, LePE 3x3 from Vt, store bf16 X ----
    #pragma unroll
    for (int qq = 0; qq < 2; ++qq) {
        const int t = qbase + qq * 16 + nn;
        const int h = t >> 3, wi = t & 7;
        #pragma unroll
        for (int nt = 0; nt < 2; ++nt) {
            const int chb = nt * 16 + q4 * 4;
            float o[4];
            #pragma unroll
            for (int r = 0; r < 4; ++r)
                o[r] = acc[qq][nt][r] * inv[qq] + cb[chb + r];
            #pragma unroll
            for (int dh = -1; dh <= 1; ++dh) {
                const int hh = h + dh;
                if (hh < 0 || hh >= RESO) continue;
                #pragma unroll
                for (int dw = -1; dw <= 1; ++dw) {
                    const int ww = wi + dw;
                    if (ww < 0 || ww >= 8) continue;
                    const int tj  = hh * 8 + ww;
                    const int wof = (dh + 1) * 3 + (dw + 1);
                    #pragma unroll
                    for (int r = 0; r < 4; ++r)
                        o[r] += cw[(chb + r) * 9 + wof] * bf2f(Vt[(chb + r) * VSTRIDE + tj]);
                }
            }
            ushort4 st;
            st.x = f2bf(o[0]); st.y = f2bf(o[1]); st.z = f2bf(o[2]); st.w = f2bf(o[3]);
            *(ushort4*)&X[((size_t)bw * WIN + t) * DIM + head * HD + chb] = st;
        }
    }
}

// ---------------------------------------------------------------------------
// Kernel 2: MFMA projection GEMM  out = X @ W^T + b, CSwin2img permuted rows.
// Grid: 512 blocks (128 m-blocks x 4 n-blocks) x 256 thr (4 waves).
// ---------------------------------------------------------------------------
__global__ __launch_bounds__(256, 4)
void proj_mfma_kernel(const unsigned short* __restrict__ X,
                      const float* __restrict__ pw,
                      const float* __restrict__ pb,
                      float* __restrict__ out)
{
    __shared__ alignas(16) unsigned short Wl[64 * WPAD];   // 33.8 KB

    const int bx   = blockIdx.x;
    const int mblk = bx >> 2;            // 0..127 -> 256 tokens each
    const int nblk = bx & 3;             // 0..3   -> 64 channels each
    const int tid  = threadIdx.x;
    const int n0   = nblk * 64;

    // ---- stage W[n0..n0+63][0..255] -> bf16 LDS (4 threads per row) ----
    {
        const int row = tid >> 2;
        const int cb0 = (tid & 3) * 64;
        #pragma unroll
        for (int c = 0; c < 64; c += 8) {
            const float4 w0 = *(const float4*)&pw[(size_t)(n0 + row) * DIM + cb0 + c];
            const float4 w1 = *(const float4*)&pw[(size_t)(n0 + row) * DIM + cb0 + c + 4];
            uint4 pk;
            pk.x = pk2(w0.x, w0.y); pk.y = pk2(w0.z, w0.w);
            pk.z = pk2(w1.x, w1.y); pk.w = pk2(w1.z, w1.w);
            *(uint4*)&Wl[row * WPAD + cb0 + c] = pk;
        }
    }
    __syncthreads();

    const int lane = tid & 63, wid = tid >> 6;
    const int q4 = lane >> 4, nn = lane & 15;
    const int mwave = mblk * 256 + wid * 64;     // 64 tokens per wave

    floatx4 acc[4][4];                            // [nt][mt]
    #pragma unroll
    for (int i = 0; i < 4; ++i)
        #pragma unroll
        for (int j = 0; j < 4; ++j)
            acc[i][j] = (floatx4){0.f, 0.f, 0.f, 0.f};

    for (int kk = 0; kk < 8; ++kk) {
        short8 af[4], bf[4];
        #pragma unroll
        for (int nt = 0; nt < 4; ++nt)
            af[nt] = *(const short8*)&Wl[(nt * 16 + nn) * WPAD + kk * 32 + q4 * 8];
        #pragma unroll
        for (int mt = 0; mt < 4; ++mt) {
            const int m = mwave + mt * 16 + nn;
            bf[mt] = *(const short8*)&X[(size_t)m * DIM + kk * 32 + q4 * 8];
        }
        #pragma unroll
        for (int nt = 0; nt < 4; ++nt)
            #pragma unroll
            for (int mt = 0; mt < 4; ++mt)
                acc[nt][mt] = __builtin_amdgcn_mfma_f32_16x16x32_bf16(af[nt], bf[mt], acc[nt][mt], 0, 0, 0);
    }

    // ---- bias + permuted store (float4 per lane per tile) ----
    float4 bias[4];
    #pragma unroll
    for (int nt = 0; nt < 4; ++nt)
        bias[nt] = *(const float4*)&pb[n0 + nt * 16 + q4 * 4];

    size_t rowoff[4];
    #pragma unroll
    for (int mt = 0; mt < 4; ++mt) {
        const int m  = mwave + mt * 16 + nn;
        const int bw = m >> 9, t = m & 511;
        const int bb = bw >> 3, wx = bw & 7, hh = t >> 3, wi = t & 7;
        rowoff[mt] = ((size_t)bb * SEQL + (size_t)hh * RESO + wx * 8 + wi) * DIM;
    }

    #pragma unroll
    for (int nt = 0; nt < 4; ++nt)
        #pragma unroll
        for (int mt = 0; mt < 4; ++mt) {
            float4 v;
            v.x = acc[nt][mt][0] + bias[nt].x;
            v.y = acc[nt][mt][1] + bias[nt].y;
            v.z = acc[nt][mt][2] + bias[nt].z;
            v.w = acc[nt][mt][3] + bias[nt].w;
            *(float4*)&out[rowoff[mt] + n0 + nt * 16 + q4 * 4] = v;
        }
}

extern "C" void kernel_launch(void* const* d_in, const int* in_sizes, int n_in,
                              void* d_out, int out_size, void* d_ws, size_t ws_size,
                              hipStream_t stream)
{
    const float* qkv    = (const float*)d_in[0];
    const float* scale  = (const float*)d_in[1];
    const float* proj_w = (const float*)d_in[2];
    const float* proj_b = (const float*)d_in[3];
    const float* conv_w = (const float*)d_in[4];
    const float* conv_b = (const float*)d_in[5];

    unsigned short* X = (unsigned short*)d_ws;   // 64*512*256 bf16 = 16 MiB

    attn_mfma_kernel<<<dim3(BATCH * NH * 8), dim3(1024), 0, stream>>>(
        qkv, scale, conv_w, conv_b, X);

    proj_mfma_kernel<<<dim3(512), dim3(256), 0, stream>>>(
        X, proj_w, proj_b, (float*)d_out);
}

// Round 2
// 213.435 us; speedup vs baseline: 1.8911x; 1.8911x over previous
//
#include <hip/hip_runtime.h>
#include <hip/hip_bf16.h>

// Problem constants (from reference)
#define BATCH 8
#define NH    8
#define HD    32
#define WIN   512    // 64 x 8 tokens per vertical-stripe window
#define DIM   256
#define RESO  64
#define SEQL  4096
#define VSTRIDE 520  // Vt padded token stride (bf16 elements)
#define WPAD  264    // proj W LDS row stride (bf16 elements)

#define LOG2E 1.44269504088896340736f

extern "C" __device__ float __ocml_native_exp2_f32(float);   // raw v_exp_f32

typedef __attribute__((ext_vector_type(8))) short short8;   // 8 bf16 (4 VGPRs) MFMA A/B frag
typedef __attribute__((ext_vector_type(4))) float floatx4;  // MFMA C/D frag

__device__ __forceinline__ unsigned short f2bf(float f) {
    union { float f; unsigned int i; } x; x.f = f;
    unsigned int r = x.i + 0x7fff + ((x.i >> 16) & 1);   // round-to-nearest-even
    return (unsigned short)(r >> 16);
}
__device__ __forceinline__ float bf2f(unsigned short u) {
    union { unsigned int i; float f; } x; x.i = ((unsigned int)u) << 16; return x.f;
}
__device__ __forceinline__ unsigned int pk2(float lo, float hi) {      // RNE pack
    return ((unsigned int)f2bf(hi) << 16) | (unsigned int)f2bf(lo);
}
__device__ __forceinline__ unsigned int pk2t(float lo, float hi) {     // truncation pack, 1 v_perm
    union { float f; unsigned int i; } a, b; a.f = lo; b.f = hi;
    return __builtin_amdgcn_perm(b.i, a.i, 0x07060302);                // {hi[3],hi[2],lo[3],lo[2]}
}

union FragU {
    unsigned int  u[4];
    unsigned short us[8];
    short8        s;
    ushort4       v4[2];
};

// ---------------------------------------------------------------------------
// MFMA flash attention + LePE. Grid: 512 blocks (64 win x 8 heads) x 512 thr
// (8 waves). Wave w owns query rows w*64..w*64+63 (4 q-tiles of 16).
// LDS 66 KiB -> 2 blocks/CU (16 waves/CU); launch_bounds(512,4) allows up to
// 128 VGPRs at that occupancy — baseline used only 52, so we spend the spare
// registers on ILP: software-prefetched kf/vf fragments + setprio around the
// MFMA/exp cluster (waves are barrier-free in the main loop, so they desync
// and the CU scheduler can arbitrate).  Round-1 lesson: 1024-thr blocks force
// VGPR<=64 -> scratch spills (WRITE_SIZE 16->491 MB). Do not go there.
// Q pre-scaled by scale*log2e -> scores in log2 domain; p = v_exp_f32.
// ---------------------------------------------------------------------------
__global__ __launch_bounds__(512, 4)
void attn_mfma_kernel(const float* __restrict__ qkv,
                      const float* __restrict__ scale_p,
                      const float* __restrict__ conv_w,
                      const float* __restrict__ conv_b,
                      unsigned short* __restrict__ X)
{
    __shared__ alignas(16) unsigned short Klds[WIN * HD];      // swizzled 16B chunks
    __shared__ alignas(16) unsigned short Vt[HD * VSTRIDE];    // V^T, padded
    __shared__ float cw[HD * 9];
    __shared__ float cb[HD];

    // XCD swizzle (512 = 8*64, bijective): blocks {x, x+8, ...} -> wh [64x,64x+64)
    // so one XCD owns 8 windows x 8 heads; heads share K/V cache lines in L2.
    const int wh_raw = blockIdx.x;
    const int wh   = ((wh_raw & 7) << 6) | (wh_raw >> 3);
    const int bw   = wh >> 3;        // global window 0..63
    const int head = wh & 7;
    const int b    = bw >> 3;
    const int wx   = bw & 7;
    const int tid  = threadIdx.x;

    const float scale = scale_p[0] * LOG2E;    // log2-domain logits
    const size_t plane = (size_t)BATCH * SEQL * DIM;
    const float* qg = qkv;
    const float* kg = qkv + plane;
    const float* vg = qkv + 2 * plane;

    // ---- Stage K (bf16 trunc, XOR-swizzled 16B chunks); static trip=4 ----
    #pragma unroll
    for (int kk = 0; kk < 4; ++kk) {
        const int idx = tid + kk * 512;
        const int t = idx >> 2, c8 = idx & 3;
        const size_t goff = ((size_t)b * SEQL + (size_t)(t >> 3) * RESO + wx * 8 + (t & 7)) * DIM
                          + head * HD + c8 * 8;
        const float4 k0 = *(const float4*)(kg + goff);
        const float4 k1 = *(const float4*)(kg + goff + 4);
        uint4 pk;
        pk.x = pk2t(k0.x, k0.y); pk.y = pk2t(k0.z, k0.w);
        pk.z = pk2t(k1.x, k1.y); pk.w = pk2t(k1.z, k1.w);
        const int p = c8 ^ ((t >> 1) & 3);
        *(uint4*)&Klds[t * HD + p * 8] = pk;
    }
    // ---- Stage V^T (bf16 RNE, padded stride); static trip=16 ----
    #pragma unroll
    for (int kk = 0; kk < 16; ++kk) {
        const int idx = tid + kk * 512;
        const int ch = idx & 31, tp = idx >> 5;
        const int t = tp * 2;
        const size_t goff = ((size_t)b * SEQL + (size_t)(t >> 3) * RESO + wx * 8 + (t & 7)) * DIM
                          + head * HD + ch;
        const float v0 = vg[goff];
        const float v1 = vg[goff + DIM];       // token t+1 (same image row)
        *(unsigned int*)&Vt[ch * VSTRIDE + t] = pk2(v0, v1);
    }
    if (tid < HD * 9) cw[tid] = conv_w[head * HD * 9 + tid];
    if (tid < HD)     cb[tid] = conv_b[head * HD + tid];

    const int lane = tid & 63, wid = tid >> 6;
    const int q4 = lane >> 4, nn = lane & 15;
    const int qbase = wid * 64;
    const bool mwin = (wx == 7);

    // ---- Q B-frags (4 q-tiles), pre-scaled, bf16 trunc; before barrier so
    //      the global-load latency overlaps the staging barrier wait ----
    short8 qf[4];
    #pragma unroll
    for (int qq = 0; qq < 4; ++qq) {
        const int t = qbase + qq * 16 + nn;
        const size_t goff = ((size_t)b * SEQL + (size_t)(t >> 3) * RESO + wx * 8 + (t & 7)) * DIM
                          + head * HD + q4 * 8;
        const float4 a = *(const float4*)(qg + goff);
        const float4 c = *(const float4*)(qg + goff + 4);
        FragU f;
        f.u[0] = pk2t(a.x * scale, a.y * scale);
        f.u[1] = pk2t(a.z * scale, a.w * scale);
        f.u[2] = pk2t(c.x * scale, c.y * scale);
        f.u[3] = pk2t(c.z * scale, c.w * scale);
        qf[qq] = f.s;
    }
    __syncthreads();

    // mask add (only stripe wx==7): key group vs query group, lane-constant
    float mk[4];
    #pragma unroll
    for (int r = 0; r < 4; ++r) {
        const bool kgrp = (((q4 * 4 + r) & 7) < 4);
        const bool qgrp = ((nn & 7) < 4);
        mk[r] = (kgrp != qgrp) ? (-100.f * LOG2E) : 0.f;
    }

    floatx4 acc[4][2];
    #pragma unroll
    for (int qq = 0; qq < 4; ++qq) {
        acc[qq][0] = (floatx4){0.f, 0.f, 0.f, 0.f};
        acc[qq][1] = (floatx4){0.f, 0.f, 0.f, 0.f};
    }
    float rs[4] = {0.f, 0.f, 0.f, 0.f};
    const floatx4 zf = (floatx4){0.f, 0.f, 0.f, 0.f};

    // K-chunk swizzle is kc-invariant: (t>>1)&3 == (nn>>1)&3 for all chunks.
    const int kswz = (q4 ^ ((nn >> 1) & 3)) * 8;
    const unsigned short* kp0 = &Klds[nn * HD + kswz];
    const unsigned short* kp1 = &Klds[(16 + nn) * HD + kswz];
    const unsigned short* vp0 = &Vt[nn * VSTRIDE + q4 * 4];
    const unsigned short* vp1 = &Vt[(16 + nn) * VSTRIDE + q4 * 4];

    // ---- prologue fragment loads (chunk 0) ----
    short8 kf0 = *(const short8*)kp0;
    short8 kf1 = *(const short8*)kp1;
    short8 vf0, vf1;
    {
        FragU f0, f1;
        f0.v4[0] = *(const ushort4*)vp0;
        f0.v4[1] = *(const ushort4*)(vp0 + 16);
        f1.v4[0] = *(const ushort4*)vp1;
        f1.v4[1] = *(const ushort4*)(vp1 + 16);
        vf0 = f0.s; vf1 = f1.s;
    }

    // ---- main K loop: 16 chunks of 32 keys; prefetch kc+1 over compute ----
    for (int kc = 0; kc < 16; ++kc) {
        const int nko = ((kc + 1) & 15) * 32;      // next-chunk token offset
        short8 nkf0 = *(const short8*)(kp0 + nko * HD);
        short8 nkf1 = *(const short8*)(kp1 + nko * HD);
        short8 nvf0, nvf1;
        {
            FragU f0, f1;
            f0.v4[0] = *(const ushort4*)(vp0 + nko);
            f0.v4[1] = *(const ushort4*)(vp0 + nko + 16);
            f1.v4[0] = *(const ushort4*)(vp1 + nko);
            f1.v4[1] = *(const ushort4*)(vp1 + nko + 16);
            nvf0 = f0.s; nvf1 = f1.s;
        }

        __builtin_amdgcn_s_setprio(1);
        #pragma unroll
        for (int qq = 0; qq < 4; ++qq) {
            floatx4 s0 = __builtin_amdgcn_mfma_f32_16x16x32_bf16(kf0, qf[qq], zf, 0, 0, 0);
            floatx4 s1 = __builtin_amdgcn_mfma_f32_16x16x32_bf16(kf1, qf[qq], zf, 0, 0, 0);
            if (mwin) {                              // wave-uniform branch (1/8 blocks)
                #pragma unroll
                for (int r = 0; r < 4; ++r) { s0[r] += mk[r]; s1[r] += mk[r]; }
            }
            float p[8];
            #pragma unroll
            for (int r = 0; r < 4; ++r) {
                p[r]     = __ocml_native_exp2_f32(s0[r]);   // single v_exp_f32
                p[4 + r] = __ocml_native_exp2_f32(s1[r]);
            }
            rs[qq] += ((p[0] + p[1]) + (p[2] + p[3])) + ((p[4] + p[5]) + (p[6] + p[7]));
            FragU pf;                                // truncation pack: 1 v_perm each
            pf.u[0] = pk2t(p[0], p[1]);
            pf.u[1] = pk2t(p[2], p[3]);
            pf.u[2] = pk2t(p[4], p[5]);
            pf.u[3] = pk2t(p[6], p[7]);
            acc[qq][0] = __builtin_amdgcn_mfma_f32_16x16x32_bf16(vf0, pf.s, acc[qq][0], 0, 0, 0);
            acc[qq][1] = __builtin_amdgcn_mfma_f32_16x16x32_bf16(vf1, pf.s, acc[qq][1], 0, 0, 0);
        }
        __builtin_amdgcn_s_setprio(0);

        kf0 = nkf0; kf1 = nkf1; vf0 = nvf0; vf1 = nvf1;
    }

    // ---- row sums across quads; lane-aligned with PV C-layout columns ----
    float inv[4];
    #pragma unroll
    for (int qq = 0; qq < 4; ++qq) {
        float v = rs[qq];
        v += __shfl_xor(v, 16);
        v += __shfl_xor(v, 32);
        inv[qq] = 1.0f / v;
    }

    // ---- epilogue: normalize, +conv bias, LePE 3x3 from Vt, store bf16 X ----
    #pragma unroll
    for (int qq = 0; qq < 4; ++qq) {
        const int t = qbase + qq * 16 + nn;
        const int h = t >> 3, wi = t & 7;
        #pragma unroll
        for (int nt = 0; nt < 2; ++nt) {
            const int chb = nt * 16 + q4 * 4;
            float o[4];
            #pragma unroll
            for (int r = 0; r < 4; ++r)
                o[r] = acc[qq][nt][r] * inv[qq] + cb[chb + r];
            #pragma unroll
            for (int dh = -1; dh <= 1; ++dh) {
                const int hh = h + dh;
                if (hh < 0 || hh >= RESO) continue;
                #pragma unroll
                for (int dw = -1; dw <= 1; ++dw) {
                    const int ww = wi + dw;
                    if (ww < 0 || ww >= 8) continue;
                    const int tj  = hh * 8 + ww;
                    const int wof = (dh + 1) * 3 + (dw + 1);
                    #pragma unroll
                    for (int r = 0; r < 4; ++r)
                        o[r] += cw[(chb + r) * 9 + wof] * bf2f(Vt[(chb + r) * VSTRIDE + tj]);
                }
            }
            ushort4 st;
            st.x = f2bf(o[0]); st.y = f2bf(o[1]); st.z = f2bf(o[2]); st.w = f2bf(o[3]);
            *(ushort4*)&X[((size_t)bw * WIN + t) * DIM + head * HD + chb] = st;
        }
    }
}

// ---------------------------------------------------------------------------
// Kernel 2: MFMA projection GEMM  out = X @ W^T + b, CSwin2img permuted rows.
// Grid: 512 blocks (128 m-blocks x 4 n-blocks) x 256 thr (4 waves).
// ---------------------------------------------------------------------------
__global__ __launch_bounds__(256, 4)
void proj_mfma_kernel(const unsigned short* __restrict__ X,
                      const float* __restrict__ pw,
                      const float* __restrict__ pb,
                      float* __restrict__ out)
{
    __shared__ alignas(16) unsigned short Wl[64 * WPAD];   // 33.8 KB

    // XCD swizzle: co-locate the 4 n-blocks of each m-slab on one XCD's L2.
    const int bx_raw = blockIdx.x;
    const int bx   = ((bx_raw & 7) << 6) | (bx_raw >> 3);
    const int mblk = bx >> 2;            // 0..127 -> 256 tokens each
    const int nblk = bx & 3;             // 0..3   -> 64 channels each
    const int tid  = threadIdx.x;
    const int n0   = nblk * 64;

    // ---- stage W[n0..n0+63][0..255] -> bf16 LDS (4 threads per row) ----
    {
        const int row = tid >> 2;
        const int cb0 = (tid & 3) * 64;
        #pragma unroll
        for (int c = 0; c < 64; c += 8) {
            const float4 w0 = *(const float4*)&pw[(size_t)(n0 + row) * DIM + cb0 + c];
            const float4 w1 = *(const float4*)&pw[(size_t)(n0 + row) * DIM + cb0 + c + 4];
            uint4 pk;
            pk.x = pk2(w0.x, w0.y); pk.y = pk2(w0.z, w0.w);
            pk.z = pk2(w1.x, w1.y); pk.w = pk2(w1.z, w1.w);
            *(uint4*)&Wl[row * WPAD + cb0 + c] = pk;
        }
    }
    __syncthreads();

    const int lane = tid & 63, wid = tid >> 6;
    const int q4 = lane >> 4, nn = lane & 15;
    const int mwave = mblk * 256 + wid * 64;     // 64 tokens per wave

    floatx4 acc[4][4];                            // [nt][mt]
    #pragma unroll
    for (int i = 0; i < 4; ++i)
        #pragma unroll
        for (int j = 0; j < 4; ++j)
            acc[i][j] = (floatx4){0.f, 0.f, 0.f, 0.f};

    for (int kk = 0; kk < 8; ++kk) {
        short8 af[4], bf[4];
        #pragma unroll
        for (int nt = 0; nt < 4; ++nt)
            af[nt] = *(const short8*)&Wl[(nt * 16 + nn) * WPAD + kk * 32 + q4 * 8];
        #pragma unroll
        for (int mt = 0; mt < 4; ++mt) {
            const int m = mwave + mt * 16 + nn;
            bf[mt] = *(const short8*)&X[(size_t)m * DIM + kk * 32 + q4 * 8];
        }
        #pragma unroll
        for (int nt = 0; nt < 4; ++nt)
            #pragma unroll
            for (int mt = 0; mt < 4; ++mt)
                acc[nt][mt] = __builtin_amdgcn_mfma_f32_16x16x32_bf16(af[nt], bf[mt], acc[nt][mt], 0, 0, 0);
    }

    // ---- bias + permuted store (float4 per lane per tile) ----
    float4 bias[4];
    #pragma unroll
    for (int nt = 0; nt < 4; ++nt)
        bias[nt] = *(const float4*)&pb[n0 + nt * 16 + q4 * 4];

    size_t rowoff[4];
    #pragma unroll
    for (int mt = 0; mt < 4; ++mt) {
        const int m  = mwave + mt * 16 + nn;
        const int bw = m >> 9, t = m & 511;
        const int bb = bw >> 3, wx = bw & 7, hh = t >> 3, wi = t & 7;
        rowoff[mt] = ((size_t)bb * SEQL + (size_t)hh * RESO + wx * 8 + wi) * DIM;
    }

    #pragma unroll
    for (int nt = 0; nt < 4; ++nt)
        #pragma unroll
        for (int mt = 0; mt < 4; ++mt) {
            float4 v;
            v.x = acc[nt][mt][0] + bias[nt].x;
            v.y = acc[nt][mt][1] + bias[nt].y;
            v.z = acc[nt][mt][2] + bias[nt].z;
            v.w = acc[nt][mt][3] + bias[nt].w;
            *(float4*)&out[rowoff[mt] + n0 + nt * 16 + q4 * 4] = v;
        }
}

extern "C" void kernel_launch(void* const* d_in, const int* in_sizes, int n_in,
                              void* d_out, int out_size, void* d_ws, size_t ws_size,
                              hipStream_t stream)
{
    const float* qkv    = (const float*)d_in[0];
    const float* scale  = (const float*)d_in[1];
    const float* proj_w = (const float*)d_in[2];
    const float* proj_b = (const float*)d_in[3];
    const float* conv_w = (const float*)d_in[4];
    const float* conv_b = (const float*)d_in[5];

    unsigned short* X = (unsigned short*)d_ws;   // 64*512*256 bf16 = 16 MiB

    attn_mfma_kernel<<<dim3(BATCH * NH * 8), dim3(512), 0, stream>>>(
        qkv, scale, conv_w, conv_b, X);

    proj_mfma_kernel<<<dim3(512), dim3(256), 0, stream>>>(
        X, proj_w, proj_b, (float*)d_out);
}